// Round 2
// baseline (580.463 us; speedup 1.0000x reference)
//
#include <hip/hip_runtime.h>
#include <cmath>

#define N_MET   100000
#define N_RXN   200000
#define E_SUB   400000
#define E_PROD  400000
#define HIDDEN  128
#define MSG_DIM 64
#define DT      0.01f
#define TGRID   96
#define TGP     97
#define NC      (N_RXN + N_MET)          // combined segment count (rxn then met)
#define NBLK    ((NC + 255) / 256)       // scan level-1 blocks = 1172
#define NPAY    (E_SUB + E_SUB + E_PROD) // 1.2M payload entries

__device__ __forceinline__ float fast_tanh(float x) {
    float t = __expf(2.0f * x);
    return 1.0f - 2.0f * __builtin_amdgcn_rcpf(t + 1.0f);
}

__device__ __forceinline__ float softplus_f(float x) {
    return (x > 20.0f) ? x : log1pf(__expf(x));
}

// ---------------- table build (unchanged, verified round 1) ----------------
__global__ void build_table(const float* __restrict__ W1, const float* __restrict__ b1,
                            const float* __restrict__ W2, const float* __restrict__ b2,
                            float* __restrict__ table) {
    __shared__ float h_s[HIDDEN];
    int p = blockIdx.x;
    int ia = p / TGP, ib = p % TGP;
    float a = (float)ia * (1.0f / TGRID);
    float b = 0.5f + (float)ib * (1.0f / TGRID);
    int lane = threadIdx.x;
    for (int j = lane; j < HIDDEN; j += 64)
        h_s[j] = tanhf(fmaf(a, W1[j], fmaf(b, W1[HIDDEN + j], b1[j])));
    __syncthreads();
    float msg = b2[lane];
    #pragma unroll 8
    for (int j = 0; j < HIDDEN; ++j)
        msg = fmaf(h_s[j], W2[j * MSG_DIM + lane], msg);
    table[p * MSG_DIM + lane] = msg;
}

// ---------------- CSR build: histogram -> scan -> scatter ----------------
__global__ void hist_kernel(const int* __restrict__ rxn_sub, const int* __restrict__ met_sub,
                            const int* __restrict__ met_prod, int* __restrict__ cnt) {
    int t = blockIdx.x * blockDim.x + threadIdx.x;
    if (t < E_SUB) {
        atomicAdd(&cnt[rxn_sub[t]], 1);
        atomicAdd(&cnt[N_RXN + met_sub[t]], 1);
    } else if (t < E_SUB + E_PROD) {
        atomicAdd(&cnt[N_RXN + met_prod[t - E_SUB]], 1);
    }
}

__global__ void scan_l1(const int* __restrict__ cnt, int* __restrict__ off,
                        int* __restrict__ bsum) {
    __shared__ int s[256];
    int t = threadIdx.x;
    int i = blockIdx.x * 256 + t;
    int v = (i < NC) ? cnt[i] : 0;
    s[t] = v;
    __syncthreads();
    #pragma unroll
    for (int d = 1; d < 256; d <<= 1) {
        int x = (t >= d) ? s[t - d] : 0;
        __syncthreads();
        s[t] += x;
        __syncthreads();
    }
    if (i < NC) off[i] = s[t] - v;         // block-local exclusive
    if (t == 255) bsum[blockIdx.x] = s[255];
}

__global__ void scan_l2(int* __restrict__ bsum) {
    __shared__ int s[256];
    __shared__ int carry_s;
    int t = threadIdx.x;
    if (t == 0) carry_s = 0;
    __syncthreads();
    for (int chunk = 0; chunk < NBLK; chunk += 256) {
        int i = chunk + t;
        int v = (i < NBLK) ? bsum[i] : 0;
        s[t] = v;
        __syncthreads();
        #pragma unroll
        for (int d = 1; d < 256; d <<= 1) {
            int x = (t >= d) ? s[t - d] : 0;
            __syncthreads();
            s[t] += x;
            __syncthreads();
        }
        int total = s[255];
        int carry = carry_s;
        if (i < NBLK) bsum[i] = carry + s[t] - v;   // exclusive + carry
        __syncthreads();
        if (t == 0) carry_s = carry + total;
        __syncthreads();
    }
}

__global__ void scan_l3(int* __restrict__ off, const int* __restrict__ bsum,
                        int* __restrict__ woff) {
    int i = blockIdx.x * blockDim.x + threadIdx.x;
    if (i < NC) {
        int w = off[i] + bsum[i >> 8];
        off[i] = w;
        woff[i] = w;
    }
}

__global__ void scatter_kernel(const int* __restrict__ rxn_sub, const int* __restrict__ met_sub,
                               const float* __restrict__ sto_sub,
                               const int* __restrict__ rxn_prod, const int* __restrict__ met_prod,
                               const float* __restrict__ sto_prod,
                               int* __restrict__ woff, int* __restrict__ pay_i,
                               float* __restrict__ pay_f) {
    int t = blockIdx.x * blockDim.x + threadIdx.x;
    if (t < E_SUB) {
        int r = rxn_sub[t], m = met_sub[t];
        int p = atomicAdd(&woff[r], 1);
        pay_i[p] = t;                                   // rxn-CSR payload: edge id
        int p2 = atomicAdd(&woff[N_RXN + m], 1);
        pay_i[p2] = r;                                  // met-CSR payload: rxn id
        pay_f[p2] = -sto_sub[t];                        // negative marks substrate
    } else if (t < E_SUB + E_PROD) {
        int e = t - E_SUB;
        int m = met_prod[e], r = rxn_prod[e];
        int p = atomicAdd(&woff[N_RXN + m], 1);
        pay_i[p] = r;
        pay_f[p] = sto_prod[e];
    }
}

// ---------------- fused edge-msg + reaction MLP ----------------
// Wave handles 2 reactions per iteration. For each reaction: gather its edges
// (lane-parallel loads), bilinear-interp the 64-dim msg (lane = msg dim),
// accumulate h in registers, then h @ V1 (register-resident) -> tanh -> @V2.
__global__ void __launch_bounds__(256, 2)
rxn_fused(const float* __restrict__ x, const int* __restrict__ met_sub,
          const float* __restrict__ sto_sub,
          const int* __restrict__ off, const int* __restrict__ cnt,
          const int* __restrict__ pay_i, const float* __restrict__ table,
          const float* __restrict__ V1, const float* __restrict__ c1,
          const float* __restrict__ V2, const float* __restrict__ c2,
          const float* __restrict__ log_k, float* __restrict__ v_out) {
    __shared__ float h_s[4][2][MSG_DIM];
    int lane  = threadIdx.x & 63;
    int wslot = threadIdx.x >> 6;
    float v1a[64], v1b[64];
    #pragma unroll
    for (int d = 0; d < 64; ++d) {
        v1a[d] = V1[d * HIDDEN + lane];
        v1b[d] = V1[d * HIDDEN + 64 + lane];
    }
    float v2a = V2[lane], v2b = V2[64 + lane];
    float c1a = c1[lane], c1b = c1[64 + lane];
    float c2v = c2[0];
    int wave   = (blockIdx.x * blockDim.x + threadIdx.x) >> 6;
    int nwaves = (gridDim.x * blockDim.x) >> 6;
    for (int r0 = wave * 2; r0 < N_RXN; r0 += nwaves * 2) {
        float es[2]; int nn[2];
        #pragma unroll
        for (int q = 0; q < 2; ++q) {
            int r = r0 + q;
            int start = off[r], n = cnt[r];
            nn[q] = n;
            float h = 0.0f;
            float xe_lane = 0.0f;
            for (int base = 0; base < n; base += 64) {
                int mchunk = n - base; if (mchunk > 64) mchunk = 64;
                float ae = 0.0f, se = 1.0f, xe = 0.0f;
                if (lane < mchunk) {
                    int eid = pay_i[start + base + lane];
                    int me  = met_sub[eid];
                    se = sto_sub[eid];
                    ae = x[me * 8 + 3];
                    xe = x[me * 8 + 4];
                }
                xe_lane += xe;
                for (int j4 = 0; j4 < mchunk; j4 += 4) {
                    #pragma unroll
                    for (int jj = 0; jj < 4; ++jj) {
                        int j = j4 + jj;
                        float a = __shfl(ae, j);
                        float b = __shfl(se, j);
                        float fa = a * (float)TGRID;
                        float fb = (b - 0.5f) * (float)TGRID;
                        int ia = (int)fa; ia = (ia < 0) ? 0 : ((ia > TGRID - 1) ? TGRID - 1 : ia);
                        int ib = (int)fb; ib = (ib < 0) ? 0 : ((ib > TGRID - 1) ? TGRID - 1 : ib);
                        float wa = fa - (float)ia;
                        float wb = fb - (float)ib;
                        const float* t00 = table + (ia * TGP + ib) * MSG_DIM;
                        float m00 = t00[lane];
                        float m01 = t00[MSG_DIM + lane];
                        float m10 = t00[TGP * MSG_DIM + lane];
                        float m11 = t00[(TGP + 1) * MSG_DIM + lane];
                        float m0  = fmaf(wb, m01 - m00, m00);
                        float m1  = fmaf(wb, m11 - m10, m10);
                        float msg = fmaf(wa, m1 - m0, m0);
                        if (j < mchunk) h += msg;
                    }
                }
            }
            // wave-reduce ext sum (lanes >= n contributed 0)
            #pragma unroll
            for (int o = 32; o > 0; o >>= 1) xe_lane += __shfl_xor(xe_lane, o);
            es[q] = xe_lane;
            h_s[wslot][q][lane] = h;
        }
        float z0a = c1a, z0b = c1b, z1a = c1a, z1b = c1b;
        #pragma unroll
        for (int d4 = 0; d4 < 64; d4 += 4) {
            float4 h0 = *(const float4*)&h_s[wslot][0][d4];
            float4 h1 = *(const float4*)&h_s[wslot][1][d4];
            z0a = fmaf(h0.x, v1a[d4 + 0], z0a); z0b = fmaf(h0.x, v1b[d4 + 0], z0b);
            z0a = fmaf(h0.y, v1a[d4 + 1], z0a); z0b = fmaf(h0.y, v1b[d4 + 1], z0b);
            z0a = fmaf(h0.z, v1a[d4 + 2], z0a); z0b = fmaf(h0.z, v1b[d4 + 2], z0b);
            z0a = fmaf(h0.w, v1a[d4 + 3], z0a); z0b = fmaf(h0.w, v1b[d4 + 3], z0b);
            z1a = fmaf(h1.x, v1a[d4 + 0], z1a); z1b = fmaf(h1.x, v1b[d4 + 0], z1b);
            z1a = fmaf(h1.y, v1a[d4 + 1], z1a); z1b = fmaf(h1.y, v1b[d4 + 1], z1b);
            z1a = fmaf(h1.z, v1a[d4 + 2], z1a); z1b = fmaf(h1.z, v1b[d4 + 2], z1b);
            z1a = fmaf(h1.w, v1a[d4 + 3], z1a); z1b = fmaf(h1.w, v1b[d4 + 3], z1b);
        }
        float p0 = fast_tanh(z0a) * v2a + fast_tanh(z0b) * v2b;
        float p1 = fast_tanh(z1a) * v2a + fast_tanh(z1b) * v2b;
        #pragma unroll
        for (int o = 32; o > 0; o >>= 1) {
            p0 += __shfl_xor(p0, o);
            p1 += __shfl_xor(p1, o);
        }
        if (lane < 2) {
            int r = r0 + lane;
            float p  = (lane == 0) ? p0 : p1;
            float bv = softplus_f(p + c2v);
            float k  = __expf(log_k[r] * 2.302585092994046f);   // 10^log_k
            int   n  = (lane == 0) ? nn[0] : nn[1];
            float e  = (lane == 0) ? es[0] : es[1];
            float em = e / fmaxf((float)n, 1.0f);
            v_out[r] = k * em * bv;
        }
    }
}

// ---------------- gather-only epilogue kernels (no atomics) ----------------
__global__ void met_scale_kernel(const float* __restrict__ x, const int* __restrict__ off,
                                 const int* __restrict__ cnt, const int* __restrict__ pay_i,
                                 const float* __restrict__ pay_f, const float* __restrict__ v,
                                 float* __restrict__ ms) {
    int i = blockIdx.x * blockDim.x + threadIdx.x;
    if (i >= N_MET) return;
    int start = off[N_RXN + i], n = cnt[N_RXN + i];
    float tot = 0.0f;
    for (int j = 0; j < n; ++j) {
        float s = pay_f[start + j];
        if (s < 0.0f) tot = fmaf(-s, v[pay_i[start + j]], tot);
    }
    tot *= DT;
    float conc = x[i * 8 + 3];
    ms[i] = (tot > 1e-12f) ? fminf(conc / tot, 1.0f) : 1.0f;
}

__global__ void rxn_scale_kernel(const int* __restrict__ off, const int* __restrict__ cnt,
                                 const int* __restrict__ pay_i, const int* __restrict__ met_sub,
                                 const float* __restrict__ ms, float* __restrict__ v) {
    int r = blockIdx.x * blockDim.x + threadIdx.x;
    if (r >= N_RXN) return;
    int start = off[r], n = cnt[r];
    float s = 1.0f;
    for (int j = 0; j < n; ++j)
        s = fminf(s, ms[met_sub[pay_i[start + j]]]);
    v[r] *= s;
}

__global__ void out_gather_kernel(const int* __restrict__ off, const int* __restrict__ cnt,
                                  const int* __restrict__ pay_i, const float* __restrict__ pay_f,
                                  const float* __restrict__ v, float* __restrict__ out) {
    int i = blockIdx.x * blockDim.x + threadIdx.x;
    if (i >= N_MET) return;
    int start = off[N_RXN + i], n = cnt[N_RXN + i];
    float acc = 0.0f;
    for (int j = 0; j < n; ++j)
        acc = fmaf(pay_f[start + j], v[pay_i[start + j]], acc);
    out[i] = acc;
}

extern "C" void kernel_launch(void* const* d_in, const int* in_sizes, int n_in,
                              void* d_out, int out_size, void* d_ws, size_t ws_size,
                              hipStream_t stream) {
    const float* x        = (const float*)d_in[0];
    const int*   met_sub  = (const int*)d_in[1];
    const int*   rxn_sub  = (const int*)d_in[2];
    const float* sto_sub  = (const float*)d_in[3];
    const int*   met_prod = (const int*)d_in[4];
    const int*   rxn_prod = (const int*)d_in[5];
    const float* sto_prod = (const float*)d_in[6];
    const float* W1       = (const float*)d_in[7];
    const float* b1       = (const float*)d_in[8];
    const float* W2       = (const float*)d_in[9];
    const float* b2       = (const float*)d_in[10];
    const float* V1       = (const float*)d_in[11];
    const float* c1       = (const float*)d_in[12];
    const float* V2       = (const float*)d_in[13];
    const float* c2       = (const float*)d_in[14];
    const float* log_k    = (const float*)d_in[15];

    int*   cnt   = (int*)d_ws;                       // NC
    int*   off   = cnt + NC;                         // NC
    int*   woff  = off + NC;                         // NC
    int*   bsum  = woff + NC;                        // NBLK (pad to 1280)
    int*   pay_i = bsum + 1280;                      // NPAY
    float* pay_f = (float*)(pay_i + NPAY);           // NPAY
    float* v     = pay_f + NPAY;                     // N_RXN
    float* ms    = v + N_RXN;                        // N_MET
    float* table = ms + N_MET;                       // TGP*TGP*64

    hipMemsetAsync(cnt, 0, NC * sizeof(int), stream);

    build_table<<<TGP * TGP, 64, 0, stream>>>(W1, b1, W2, b2, table);
    hist_kernel<<<(E_SUB + E_PROD + 255) / 256, 256, 0, stream>>>(rxn_sub, met_sub, met_prod, cnt);
    scan_l1<<<NBLK, 256, 0, stream>>>(cnt, off, bsum);
    scan_l2<<<1, 256, 0, stream>>>(bsum);
    scan_l3<<<NBLK, 256, 0, stream>>>(off, bsum, woff);
    scatter_kernel<<<(E_SUB + E_PROD + 255) / 256, 256, 0, stream>>>(
        rxn_sub, met_sub, sto_sub, rxn_prod, met_prod, sto_prod, woff, pay_i, pay_f);
    rxn_fused<<<768, 256, 0, stream>>>(x, met_sub, sto_sub, off, cnt, pay_i, table,
                                       V1, c1, V2, c2, log_k, v);
    met_scale_kernel<<<(N_MET + 255) / 256, 256, 0, stream>>>(x, off, cnt, pay_i, pay_f, v, ms);
    rxn_scale_kernel<<<(N_RXN + 255) / 256, 256, 0, stream>>>(off, cnt, pay_i, met_sub, ms, v);
    out_gather_kernel<<<(N_MET + 255) / 256, 256, 0, stream>>>(off, cnt, pay_i, pay_f, v, (float*)d_out);
}

// Round 3
// 434.451 us; speedup vs baseline: 1.3361x; 1.3361x over previous
//
#include <hip/hip_runtime.h>
#include <cmath>

#define N_MET   100000
#define N_RXN   200000
#define E_SUB   400000
#define E_PROD  400000
#define HIDDEN  128
#define MSG_DIM 64
#define DT      0.01f
#define TGRID   64
#define TGP     65
#define NPTS    (TGP * TGP)
#define BPTS    16
#define NB1     ((N_RXN + 255) / 256)    // 782 scan blocks

__device__ __forceinline__ float fast_tanh(float x) {
    float t = __expf(2.0f * x);
    return 1.0f - 2.0f * __builtin_amdgcn_rcpf(t + 1.0f);
}

__device__ __forceinline__ float softplus_f(float x) {
    return (x > 20.0f) ? x : log1pf(__expf(x));
}

// M[j][d] = sum_m W2[j][m] * V1[m][d]  (128x128), row 128 = b2 @ V1 bias
__global__ void mm_kernel(const float* __restrict__ W2, const float* __restrict__ V1,
                          const float* __restrict__ b2, float* __restrict__ M) {
    int j = blockIdx.x;      // 0..128
    int d = threadIdx.x;     // 0..127
    float acc = 0.0f;
    if (j < HIDDEN) {
        for (int m = 0; m < MSG_DIM; ++m)
            acc = fmaf(W2[j * MSG_DIM + m], V1[m * HIDDEN + d], acc);
        M[j * HIDDEN + d] = acc;
    } else {
        for (int m = 0; m < MSG_DIM; ++m)
            acc = fmaf(b2[m], V1[m * HIDDEN + d], acc);
        M[HIDDEN * HIDDEN + d] = acc;
    }
}

// g-table: t2[(ia*TGP+ib)*64 + l] = { g[l], g[l+64] } where
// g(a,b) = tanh(a*W1[0]+b*W1[1]+b1) @ M + bg.  M column register-resident.
__global__ void __launch_bounds__(128)
gtable_kernel(const float* __restrict__ W1, const float* __restrict__ b1,
              const float* __restrict__ M, float* __restrict__ t2f) {
    __shared__ float h_s[HIDDEN];
    int d = threadIdx.x;
    float Mreg[HIDDEN];
    #pragma unroll 8
    for (int j = 0; j < HIDDEN; ++j) Mreg[j] = M[j * HIDDEN + d];
    float bgd = M[HIDDEN * HIDDEN + d];
    float w1a = W1[d], w1b = W1[HIDDEN + d], b1d = b1[d];
    int pend = blockIdx.x * BPTS + BPTS; if (pend > NPTS) pend = NPTS;
    for (int p = blockIdx.x * BPTS; p < pend; ++p) {
        int ia = p / TGP, ib = p % TGP;
        float a = (float)ia * (1.0f / TGRID);
        float b = 0.5f + (float)ib * (1.0f / TGRID);
        h_s[d] = tanhf(fmaf(a, w1a, fmaf(b, w1b, b1d)));
        __syncthreads();
        float acc = bgd;
        #pragma unroll
        for (int j4 = 0; j4 < HIDDEN; j4 += 4) {
            float4 hv = *(const float4*)&h_s[j4];
            acc = fmaf(hv.x, Mreg[j4 + 0], acc);
            acc = fmaf(hv.y, Mreg[j4 + 1], acc);
            acc = fmaf(hv.z, Mreg[j4 + 2], acc);
            acc = fmaf(hv.w, Mreg[j4 + 3], acc);
        }
        if (d < 64) t2f[(p * 64 + d) * 2]          = acc;
        else        t2f[(p * 64 + (d - 64)) * 2 + 1] = acc;
        __syncthreads();
    }
}

// Per substrate edge: count + ext accumulation per reaction.
__global__ void hist_kernel(const int* __restrict__ rxn_sub, const int* __restrict__ met_sub,
                            const float* __restrict__ x,
                            int* __restrict__ cnt, float* __restrict__ ext_sum) {
    int t = blockIdx.x * blockDim.x + threadIdx.x;
    if (t < E_SUB) {
        int r = rxn_sub[t];
        atomicAdd(&cnt[r], 1);
        atomicAdd(&ext_sum[r], x[met_sub[t] * 8 + 4]);
    }
}

__global__ void scan_l1(const int* __restrict__ cnt, int* __restrict__ off,
                        int* __restrict__ bsum) {
    __shared__ int s[256];
    int t = threadIdx.x;
    int i = blockIdx.x * 256 + t;
    int v = (i < N_RXN) ? cnt[i] : 0;
    s[t] = v;
    __syncthreads();
    #pragma unroll
    for (int d = 1; d < 256; d <<= 1) {
        int q = (t >= d) ? s[t - d] : 0;
        __syncthreads();
        s[t] += q;
        __syncthreads();
    }
    if (i < N_RXN) off[i] = s[t] - v;
    if (t == 255) bsum[blockIdx.x] = s[255];
}

__global__ void scan_l2(int* __restrict__ bsum) {
    __shared__ int s[256];
    __shared__ int carry_s;
    int t = threadIdx.x;
    if (t == 0) carry_s = 0;
    __syncthreads();
    for (int chunk = 0; chunk < NB1; chunk += 256) {
        int i = chunk + t;
        int v = (i < NB1) ? bsum[i] : 0;
        s[t] = v;
        __syncthreads();
        #pragma unroll
        for (int d = 1; d < 256; d <<= 1) {
            int q = (t >= d) ? s[t - d] : 0;
            __syncthreads();
            s[t] += q;
            __syncthreads();
        }
        int total = s[255];
        int carry = carry_s;
        if (i < NB1) bsum[i] = carry + s[t] - v;
        __syncthreads();
        if (t == 0) carry_s = carry + total;
        __syncthreads();
    }
}

// finalize scan; also init rxn_scale slot (vf[2r+1]) to 1.0f
__global__ void scan_l3(int* __restrict__ off, const int* __restrict__ bsum,
                        int* __restrict__ woff, float* __restrict__ vf) {
    int i = blockIdx.x * blockDim.x + threadIdx.x;
    if (i < N_RXN) {
        int w = off[i] + bsum[i >> 8];
        off[i] = w;
        woff[i] = w;
        vf[2 * i + 1] = 1.0f;
    }
    if (i == 0) off[N_RXN] = E_SUB;
}

__global__ void scatter_kernel(const int* __restrict__ rxn_sub,
                               int* __restrict__ woff, int* __restrict__ pay) {
    int t = blockIdx.x * blockDim.x + threadIdx.x;
    if (t < E_SUB) {
        int p = atomicAdd(&woff[rxn_sub[t]], 1);
        pay[p] = t;
    }
}

// Wave handles 32 consecutive reactions: edges batch-loaded 64 at a time
// (full lane utilization), shfl-broadcast per edge, 128-dim g interp with
// lane = 2 dims, inline wave-uniform finalize at segment boundaries.
__global__ void __launch_bounds__(256)
rxn_fused2(const float* __restrict__ x, const int* __restrict__ met_sub,
           const float* __restrict__ sto_sub,
           const int* __restrict__ off, const int* __restrict__ pay,
           const float2* __restrict__ t2,
           const float* __restrict__ c1, const float* __restrict__ V2,
           const float* __restrict__ c2, const float* __restrict__ log_k,
           const float* __restrict__ ext_sum, float* __restrict__ vf) {
    int lane = threadIdx.x & 63;
    int wave = (blockIdx.x * blockDim.x + threadIdx.x) >> 6;
    int nwaves = (gridDim.x * blockDim.x) >> 6;
    float c1a = c1[lane], c1b = c1[64 + lane];
    float v2a = V2[lane], v2b = V2[64 + lane];
    float c2v = c2[0];
    for (int chunk = wave; chunk * 32 < N_RXN; chunk += nwaves) {
        int r0 = chunk * 32;
        int offs = (lane <= 32) ? off[r0 + lane] : 0;
        int start = __shfl(offs, 0);
        int end   = __shfl(offs, 32);
        int cur = 0;
        int cur_start = start;
        int cur_end = __shfl(offs, 1);
        float za = c1a, zb = c1b;
        for (int p0 = start; p0 < end; p0 += 64) {
            int nchunk = end - p0; if (nchunk > 64) nchunk = 64;
            float ae = 0.0f, se = 1.0f;
            if (lane < nchunk) {
                int eid = pay[p0 + lane];
                se = sto_sub[eid];
                ae = x[met_sub[eid] * 8 + 3];
            }
            for (int j = 0; j < nchunk; ++j) {
                int pe = p0 + j;
                while (pe >= cur_end) {          // wave-uniform finalize
                    float pp = fast_tanh(za) * v2a + fast_tanh(zb) * v2b;
                    #pragma unroll
                    for (int o = 32; o > 0; o >>= 1) pp += __shfl_xor(pp, o);
                    int r = r0 + cur;
                    float bv = softplus_f(pp + c2v);
                    float k  = __expf(log_k[r] * 2.302585092994046f);
                    int n = cur_end - cur_start;
                    float em = ext_sum[r] / (float)(n > 0 ? n : 1);
                    if (lane == 0) vf[2 * r] = k * em * bv;
                    cur++;
                    cur_start = cur_end;
                    cur_end = __shfl(offs, cur + 1);
                    za = c1a; zb = c1b;
                }
                float a = __shfl(ae, j);
                float b = __shfl(se, j);
                float fa = a * (float)TGRID;
                float fb = (b - 0.5f) * (float)TGRID;
                int ia = (int)fa; ia = ia < 0 ? 0 : (ia > TGRID - 1 ? TGRID - 1 : ia);
                int ib = (int)fb; ib = ib < 0 ? 0 : (ib > TGRID - 1 ? TGRID - 1 : ib);
                float wa = fa - (float)ia;
                float wb = fb - (float)ib;
                const float2* tp = t2 + (ia * TGP + ib) * 64 + lane;
                float2 m00 = tp[0];
                float2 m01 = tp[64];
                float2 m10 = tp[TGP * 64];
                float2 m11 = tp[TGP * 64 + 64];
                float g0x = fmaf(wb, m01.x - m00.x, m00.x);
                float g0y = fmaf(wb, m01.y - m00.y, m00.y);
                float g1x = fmaf(wb, m11.x - m10.x, m10.x);
                float g1y = fmaf(wb, m11.y - m10.y, m10.y);
                za += fmaf(wa, g1x - g0x, g0x);
                zb += fmaf(wa, g1y - g0y, g0y);
            }
        }
        while (cur < 32) {                       // tail finalize
            float pp = fast_tanh(za) * v2a + fast_tanh(zb) * v2b;
            #pragma unroll
            for (int o = 32; o > 0; o >>= 1) pp += __shfl_xor(pp, o);
            int r = r0 + cur;
            float bv = softplus_f(pp + c2v);
            float k  = __expf(log_k[r] * 2.302585092994046f);
            int n = cur_end - cur_start;
            float em = ext_sum[r] / (float)(n > 0 ? n : 1);
            if (lane == 0) vf[2 * r] = k * em * bv;
            cur++;
            if (cur < 32) {
                cur_start = cur_end;
                cur_end = __shfl(offs, cur + 1);
                za = c1a; zb = c1b;
            }
        }
    }
}

__global__ void cons_kernel(const int* __restrict__ met_sub, const int* __restrict__ rxn_sub,
                            const float* __restrict__ sto_sub, const float* __restrict__ vf,
                            float* __restrict__ tot) {
    int e = blockIdx.x * blockDim.x + threadIdx.x;
    if (e < E_SUB)
        atomicAdd(&tot[met_sub[e]], sto_sub[e] * vf[2 * rxn_sub[e]] * DT);
}

__global__ void rxn_min_kernel(const int* __restrict__ met_sub, const int* __restrict__ rxn_sub,
                               const float* __restrict__ x, const float* __restrict__ tot,
                               float* __restrict__ vf) {
    int e = blockIdx.x * blockDim.x + threadIdx.x;
    if (e < E_SUB) {
        int m = met_sub[e];
        float tc = tot[m];
        float s = 1.0f;
        if (tc > 1e-12f) s = fminf(x[m * 8 + 3] / tc, 1.0f);
        // s in [0,1] (non-negative) -> uint compare == float compare
        atomicMin((unsigned int*)&vf[2 * rxn_sub[e] + 1], __float_as_uint(s));
    }
}

__global__ void out_kernel(const int* __restrict__ met_sub, const int* __restrict__ rxn_sub,
                           const float* __restrict__ sto_sub,
                           const int* __restrict__ met_prod, const int* __restrict__ rxn_prod,
                           const float* __restrict__ sto_prod,
                           const float2* __restrict__ vrs, float* __restrict__ out) {
    int t = blockIdx.x * blockDim.x + threadIdx.x;
    if (t < E_SUB) {
        float2 vr = vrs[rxn_sub[t]];
        atomicAdd(&out[met_sub[t]], -sto_sub[t] * vr.x * vr.y);
    } else if (t < E_SUB + E_PROD) {
        int e = t - E_SUB;
        float2 vr = vrs[rxn_prod[e]];
        atomicAdd(&out[met_prod[e]], sto_prod[e] * vr.x * vr.y);
    }
}

extern "C" void kernel_launch(void* const* d_in, const int* in_sizes, int n_in,
                              void* d_out, int out_size, void* d_ws, size_t ws_size,
                              hipStream_t stream) {
    const float* x        = (const float*)d_in[0];
    const int*   met_sub  = (const int*)d_in[1];
    const int*   rxn_sub  = (const int*)d_in[2];
    const float* sto_sub  = (const float*)d_in[3];
    const int*   met_prod = (const int*)d_in[4];
    const int*   rxn_prod = (const int*)d_in[5];
    const float* sto_prod = (const float*)d_in[6];
    const float* W1       = (const float*)d_in[7];
    const float* b1       = (const float*)d_in[8];
    const float* W2       = (const float*)d_in[9];
    const float* b2       = (const float*)d_in[10];
    const float* V1       = (const float*)d_in[11];
    const float* c1       = (const float*)d_in[12];
    const float* V2       = (const float*)d_in[13];
    const float* c2       = (const float*)d_in[14];
    const float* log_k    = (const float*)d_in[15];

    int*   cnt     = (int*)d_ws;                         // N_RXN
    float* tot     = (float*)(cnt + N_RXN);              // N_MET
    float* ext_sum = tot + N_MET;                        // N_RXN
    int*   off     = (int*)(ext_sum + N_RXN);            // N_RXN + 1
    int*   woff    = off + N_RXN + 1;                    // N_RXN
    int*   bsum    = woff + N_RXN;                       // 1024
    int*   pay     = bsum + 1024;                        // E_SUB
    float* vf      = (float*)(pay + E_SUB);              // 2*N_RXN (float2: v, rxn_scale)
    float* M       = vf + 2 * (size_t)N_RXN;             // 128*128 + 128
    float* t2f     = M + HIDDEN * HIDDEN + HIDDEN;       // NPTS*128

    // zero cnt | tot | ext_sum (contiguous) and d_out
    hipMemsetAsync(cnt, 0, (size_t)(2 * N_RXN + N_MET) * sizeof(int), stream);
    hipMemsetAsync(d_out, 0, (size_t)N_MET * sizeof(float), stream);

    mm_kernel<<<HIDDEN + 1, HIDDEN, 0, stream>>>(W2, V1, b2, M);
    gtable_kernel<<<(NPTS + BPTS - 1) / BPTS, HIDDEN, 0, stream>>>(W1, b1, M, t2f);
    hist_kernel<<<(E_SUB + 255) / 256, 256, 0, stream>>>(rxn_sub, met_sub, x, cnt, ext_sum);
    scan_l1<<<NB1, 256, 0, stream>>>(cnt, off, bsum);
    scan_l2<<<1, 256, 0, stream>>>(bsum);
    scan_l3<<<NB1, 256, 0, stream>>>(off, bsum, woff, vf);
    scatter_kernel<<<(E_SUB + 255) / 256, 256, 0, stream>>>(rxn_sub, woff, pay);
    rxn_fused2<<<1563, 256, 0, stream>>>(x, met_sub, sto_sub, off, pay, (const float2*)t2f,
                                         c1, V2, c2, log_k, ext_sum, vf);
    cons_kernel<<<(E_SUB + 255) / 256, 256, 0, stream>>>(met_sub, rxn_sub, sto_sub, vf, tot);
    rxn_min_kernel<<<(E_SUB + 255) / 256, 256, 0, stream>>>(met_sub, rxn_sub, x, tot, vf);
    out_kernel<<<(E_SUB + E_PROD + 255) / 256, 256, 0, stream>>>(
        met_sub, rxn_sub, sto_sub, met_prod, rxn_prod, sto_prod, (const float2*)vf, (float*)d_out);
}